// Round 8
// baseline (99.694 us; speedup 1.0000x reference)
//
#include <hip/hip_runtime.h>

// ChamferLoss: x,y (16,4096,3) f32 -> scalar.
// R16: R15 passed (absmax 0.0) -> all MFMA machinery verified; R13/R14's
// shared ~0.084 failure is localized to the in-block js-loop (R14 had no
// transport and still failed). R15's cost: 32x-redundant in-block db
// packing (~240 VALU instrs/thread) + serial load->pack->LDS chain;
// MfmaUtil 12.5%, true VALU ~30% -> no pipe saturated.
// Fix: chamfer_pack packs each point's B-frags ONCE into 4MB ws (min-region
// init folded in); chamfer_dir is R15-VERBATIM (one slice/block, no js
// loop, in-kernel A-pack, atomicMin transport) except staging = plain
// 8x16B copy of prepacked frags. Only new code vs passing R15 = the
// B-transport (audited: unit (p>>10)*2048+((p>>5)&31)*64+(p&31), h1 at
// +32 == R15's LDS layout exactly).
// Target: dir 12-18us, pack 3-5us, dur_us 62-70.

#define NP 4096
#define NB 16
#define BLK 256
#define NBLOCKS 4096            // dir(2) x b(16) x js(4) x ic(32)

typedef float f32x16 __attribute__((ext_vector_type(16)));
typedef short s16x8 __attribute__((ext_vector_type(8)));

// ws layout:
//   u32 [0, 131072): per-query running min (uint-cast f32):
//                    dir*65536 + b*4096 + q        (512 KB)
//   s16x8 units starting at U0 = 32768 (byte 512K):
//     XB @ +0      : [b][8192]  B-frags of x points (2 MB)
//     YB @ +131072 : [b][8192]  B-frags of y points (2 MB)
#define U0 32768

__device__ __forceinline__ float fmin3f(float a, float b, float c) {
  float d;
  asm("v_min3_f32 %0, %1, %2, %3" : "=v"(d) : "v"(a), "v"(b), "v"(c));
  return d;
}

__device__ __forceinline__ unsigned short f2bf(float v) {
  unsigned u = __float_as_uint(v);
  u += 0x7FFFu + ((u >> 16) & 1u);        // RNE to bf16
  return (unsigned short)(u >> 16);
}
__device__ __forceinline__ float bf2f(unsigned short s) {
  return __uint_as_float(((unsigned)s) << 16);
}

// K-slot layout (A = queries as rows, B = db points as cols), R12/R15-verified:
//  k0-2 : sh(x,y,z)*dh(x,y,z)   (s = -2*q, hi)    k9,10 : 1*d2h, 1*d2l
//  k3-5 : sh*dl                                   k11,12: q2h*1, q2l*1
//  k6-8 : sl*dh                                   k13-15: 0
// A-frag lane l: row=l%32, k=(l/32)*8+i ; B-frag: col=l%32, k=(l/32)*8+i.
// C/D: col=lane&31, row=(reg&3)+8*(reg>>2)+4*(lane>>5).

__global__ __launch_bounds__(256) void chamfer_pack(
    const float* __restrict__ x, const float* __restrict__ y,
    unsigned* __restrict__ wsmin, s16x8* __restrict__ wsfrag,
    float* __restrict__ out) {
  const int gid = blockIdx.x * 256 + threadIdx.x;   // grid 512 -> 131072
  if (gid == 0) out[0] = 0.0f;
  wsmin[gid] = 0x7F800000u;                         // +inf (min-region init)

  const int isY = gid >> 16;
  const int idx = gid & 65535;        // b*4096 + p
  const int p   = idx & 4095;
  const short ONE = (short)0x3F80;

  const float* src = (isY ? y : x) + (size_t)idx * 3;
  const float y0 = src[0], y1 = src[1], y2 = src[2];

  // B-frag packing (R15-verbatim values)
  const unsigned short dh0 = f2bf(y0), dh1 = f2bf(y1), dh2 = f2bf(y2);
  const unsigned short dl0 = f2bf(y0 - bf2f(dh0));
  const unsigned short dl1 = f2bf(y1 - bf2f(dh1));
  const unsigned short dl2 = f2bf(y2 - bf2f(dh2));
  const float d2 = fmaf(y0, y0, fmaf(y1, y1, y2 * y2));
  const unsigned short d2h = f2bf(d2);
  const unsigned short d2l = f2bf(d2 - bf2f(d2h));
  const s16x8 h0 = {(short)dh0, (short)dh1, (short)dh2,
                    (short)dl0, (short)dl1, (short)dl2,
                    (short)dh0, (short)dh1};
  const s16x8 h1 = {(short)dh2, (short)d2h, (short)d2l, ONE, ONE, 0, 0, 0};

  // unit within [b] region: matches R15's LDS layout frag[jt*64 + jc] (+32 for h1)
  const int u = (p >> 10) * 2048 + ((p >> 5) & 31) * 64 + (p & 31);
  s16x8* B = wsfrag + (isY ? 131072 : 0) + (size_t)(idx - p) * 2;  // (idx-p)*2 = b*8192
  B[u]      = h0;
  B[u + 32] = h1;
}

__global__ __launch_bounds__(BLK) void chamfer_dir(
    const float* __restrict__ x, const float* __restrict__ y,
    const s16x8* __restrict__ wsfrag, unsigned* __restrict__ wsmin) {
  const int bid = blockIdx.x;
  const int dir = bid >> 11;
  const int b   = (bid >> 7) & 15;
  const int js  = (bid >> 5) & 3;
  const int ic  = bid & 31;

  // dir 0: queries = x rows, db = y cols (reference min1)
  // dir 1: queries = y rows, db = x cols (reference min2)
  const float* q_base = (dir == 0 ? x : y) + (size_t)b * NP * 3;
  const s16x8* dB = wsfrag + (dir == 0 ? 131072 : 0) + (size_t)b * 8192;

  __shared__ s16x8 yfrag[2048];       // 32 KB: this block's 1024-pt db slice
  __shared__ float m1s[128];

  const int tid  = threadIdx.x;
  const int lane = tid & 63;
  const int w    = tid >> 6;
  const int row  = lane & 31;
  const int hf   = lane >> 5;
  const short ONE = (short)0x3F80;    // bf16(1.0)

  // ---- A-frag: this lane's query point (R15-verbatim in-kernel pack) ----
  const int qi = ic * 128 + w * 32 + row;
  const float qx = q_base[qi * 3 + 0];
  const float qy = q_base[qi * 3 + 1];
  const float qz = q_base[qi * 3 + 2];
  const float sx = -2.0f * qx, sy = -2.0f * qy, sz = -2.0f * qz;
  const unsigned short shx = f2bf(sx), shy = f2bf(sy), shz = f2bf(sz);
  const unsigned short slx = f2bf(sx - bf2f(shx));
  const unsigned short sly = f2bf(sy - bf2f(shy));
  const unsigned short slz = f2bf(sz - bf2f(shz));
  const float q2 = fmaf(qx, qx, fmaf(qy, qy, qz * qz));
  const unsigned short q2h = f2bf(q2);
  const unsigned short q2l = f2bf(q2 - bf2f(q2h));
  const s16x8 a0 = {(short)shx, (short)shy, (short)shz,
                    (short)shx, (short)shy, (short)shz,
                    (short)slx, (short)sly};
  const s16x8 a1 = {(short)slz, ONE, ONE, (short)q2h, (short)q2l, 0, 0, 0};
  const s16x8 afr = hf ? a1 : a0;

  // ---- stage this js slice: plain copy of prepacked frags ----
#pragma unroll
  for (int k = 0; k < 8; ++k)
    yfrag[tid + k * 256] = dB[js * 2048 + tid + k * 256];
  __syncthreads();

  // ---- MFMA inner loop (R15-verbatim) ----
  float m1[16];
#pragma unroll
  for (int r = 0; r < 16; ++r) m1[r] = 3.4e38f;
  const f32x16 zc = {};
  const s16x8* base = &yfrag[0] + lane;     // ds addr = lane*16 + jt*1024 (imm)

#pragma unroll
  for (int jt = 0; jt < 32; jt += 2) {
    const s16x8 b0 = base[jt * 64];
    const s16x8 b1 = base[(jt + 1) * 64];
    const f32x16 d0 = __builtin_amdgcn_mfma_f32_32x32x16_bf16(afr, b0, zc, 0, 0, 0);
    const f32x16 d1 = __builtin_amdgcn_mfma_f32_32x32x16_bf16(afr, b1, zc, 0, 0, 0);
#pragma unroll
    for (int r = 0; r < 16; ++r) m1[r] = fmin3f(d0[r], d1[r], m1[r]);
  }

  // ---- min across the 32 cols (R15-verbatim) ----
#pragma unroll
  for (int s = 1; s <= 16; s <<= 1) {
#pragma unroll
    for (int r = 0; r < 16; ++r) m1[r] = fminf(m1[r], __shfl_xor(m1[r], s));
  }

  // ---- park row mins in m1s (R15-verbatim) ----
  if ((lane & 31) == 0) {
#pragma unroll
    for (int r = 0; r < 16; ++r) {
      const int rw = (r & 3) + 8 * (r >> 2) + 4 * hf;
      m1s[w * 32 + rw] = m1[r];
    }
  }
  __syncthreads();

  // ---- cross-block combine via atomicMin on uint-cast floats (R15-verbatim) ----
  if (tid < 128) {
    const float v = fmaxf(m1s[tid], 0.0f);
    atomicMin(&wsmin[(size_t)dir * 65536 + (size_t)b * NP + ic * 128 + tid],
              __float_as_uint(v));
  }
}

__global__ __launch_bounds__(256) void chamfer_final(
    const unsigned* __restrict__ wsmin, float* __restrict__ out) {
  const int i = blockIdx.x * 256 + threadIdx.x;   // grid 512 -> 131072
  float s = sqrtf(__uint_as_float(wsmin[i]) + 1e-6f);
#pragma unroll
  for (int off = 32; off > 0; off >>= 1) s += __shfl_down(s, off);
  __shared__ float wsum[4];
  if ((threadIdx.x & 63) == 0) wsum[threadIdx.x >> 6] = s;
  __syncthreads();
  if (threadIdx.x == 0)
    atomicAdd(out, (wsum[0] + wsum[1] + wsum[2] + wsum[3]) * (1.0f / 65536.0f));
}

extern "C" void kernel_launch(void* const* d_in, const int* in_sizes, int n_in,
                              void* d_out, int out_size, void* d_ws, size_t ws_size,
                              hipStream_t stream) {
  const float* x = (const float*)d_in[0];
  const float* y = (const float*)d_in[1];
  float* out = (float*)d_out;
  unsigned* wsmin = (unsigned*)d_ws;              // 512 KB
  s16x8* wsfrag = (s16x8*)d_ws + U0;              // 4 MB of B-frags after it

  chamfer_pack<<<512, 256, 0, stream>>>(x, y, wsmin, wsfrag, out);
  chamfer_dir<<<NBLOCKS, BLK, 0, stream>>>(x, y, wsfrag, wsmin);
  chamfer_final<<<512, 256, 0, stream>>>(wsmin, out);
}

// Round 11
// 99.513 us; speedup vs baseline: 1.0018x; 1.0018x over previous
//
#include <hip/hip_runtime.h>

// ChamferLoss: x,y (16,4096,3) f32 -> scalar.
// R19: R18 (semantically == passing R16 + scheduling-only changes) FAILED
// -> re-correlate all MFMA rounds: every kernel with __launch_bounds__(N,4)
// failed (R13 .087, R14 .084, R17 .012, R18 .053); every one without the
// min-waves arg passed (R12, R15, R16 absmax 0.0). 4/4 vs 3/3.
// Theory: min-waves=4 raises the VGPR budget to 128 -> compiler assigns
// MFMA results to AGPR-class regs; the v_accvgpr copies around the inline
// v_min3_f32 asm (or MFMA scheduling under the relaxed budget) miscompile.
// R19 = R18 with the min-waves arg REMOVED. Single-variable diff vs both
// anchors: vs R18 only launch_bounds; vs R16 only the UB-free wrap
// prefetch. Pass -> (,4) confirmed as trigger, prefetch perf measured.
// Fail -> prefetch implicated, revert next.
// Target if prefetch helps: dir 20-32us, dur_us 80-92.

#define NP 4096
#define NB 16
#define BLK 256
#define NBLOCKS 4096            // dir(2) x b(16) x js(4) x ic(32)

typedef float f32x16 __attribute__((ext_vector_type(16)));
typedef short s16x8 __attribute__((ext_vector_type(8)));

// ws layout:
//   u32 [0, 131072): per-query running min (uint-cast f32):
//                    dir*65536 + b*4096 + q        (512 KB)
//   s16x8 units starting at U0 = 32768 (byte 512K):
//     XB @ +0      : [b][8192]  B-frags of x points (2 MB)
//     YB @ +131072 : [b][8192]  B-frags of y points (2 MB)
#define U0 32768

__device__ __forceinline__ float fmin3f(float a, float b, float c) {
  float d;
  asm("v_min3_f32 %0, %1, %2, %3" : "=v"(d) : "v"(a), "v"(b), "v"(c));
  return d;
}

__device__ __forceinline__ unsigned short f2bf(float v) {
  unsigned u = __float_as_uint(v);
  u += 0x7FFFu + ((u >> 16) & 1u);        // RNE to bf16
  return (unsigned short)(u >> 16);
}
__device__ __forceinline__ float bf2f(unsigned short s) {
  return __uint_as_float(((unsigned)s) << 16);
}

// K-slot layout (A = queries as rows, B = db points as cols), R12/R15/R16-verified:
//  k0-2 : sh(x,y,z)*dh(x,y,z)   (s = -2*q, hi)    k9,10 : 1*d2h, 1*d2l
//  k3-5 : sh*dl                                   k11,12: q2h*1, q2l*1
//  k6-8 : sl*dh                                   k13-15: 0
// A-frag lane l: row=l%32, k=(l/32)*8+i ; B-frag: col=l%32, k=(l/32)*8+i.
// C/D: col=lane&31, row=(reg&3)+8*(reg>>2)+4*(lane>>5).

__global__ __launch_bounds__(256) void chamfer_pack(
    const float* __restrict__ x, const float* __restrict__ y,
    unsigned* __restrict__ wsmin, s16x8* __restrict__ wsfrag,
    float* __restrict__ out) {
  const int gid = blockIdx.x * 256 + threadIdx.x;   // grid 512 -> 131072
  if (gid == 0) out[0] = 0.0f;
  wsmin[gid] = 0x7F800000u;                         // +inf (min-region init)

  const int isY = gid >> 16;
  const int idx = gid & 65535;        // b*4096 + p
  const int p   = idx & 4095;
  const short ONE = (short)0x3F80;

  const float* src = (isY ? y : x) + (size_t)idx * 3;
  const float y0 = src[0], y1 = src[1], y2 = src[2];

  const unsigned short dh0 = f2bf(y0), dh1 = f2bf(y1), dh2 = f2bf(y2);
  const unsigned short dl0 = f2bf(y0 - bf2f(dh0));
  const unsigned short dl1 = f2bf(y1 - bf2f(dh1));
  const unsigned short dl2 = f2bf(y2 - bf2f(dh2));
  const float d2 = fmaf(y0, y0, fmaf(y1, y1, y2 * y2));
  const unsigned short d2h = f2bf(d2);
  const unsigned short d2l = f2bf(d2 - bf2f(d2h));
  const s16x8 h0 = {(short)dh0, (short)dh1, (short)dh2,
                    (short)dl0, (short)dl1, (short)dl2,
                    (short)dh0, (short)dh1};
  const s16x8 h1 = {(short)dh2, (short)d2h, (short)d2l, ONE, ONE, 0, 0, 0};

  // unit within [b] region: matches dir kernel's LDS layout (+32 for h1)
  const int u = (p >> 10) * 2048 + ((p >> 5) & 31) * 64 + (p & 31);
  s16x8* B = wsfrag + (isY ? 131072 : 0) + (size_t)(idx - p) * 2;  // b*8192
  B[u]      = h0;
  B[u + 32] = h1;
}

__global__ __launch_bounds__(BLK) void chamfer_dir(
    const float* __restrict__ x, const float* __restrict__ y,
    const s16x8* __restrict__ wsfrag, unsigned* __restrict__ wsmin) {
  const int bid = blockIdx.x;
  const int dir = bid >> 11;
  const int b   = (bid >> 7) & 15;
  const int js  = (bid >> 5) & 3;
  const int ic  = bid & 31;

  // dir 0: queries = x rows, db = y cols (reference min1)
  // dir 1: queries = y rows, db = x cols (reference min2)
  const float* q_base = (dir == 0 ? x : y) + (size_t)b * NP * 3;
  const s16x8* dB = wsfrag + (dir == 0 ? 131072 : 0) + (size_t)b * 8192;

  __shared__ s16x8 yfrag[2048];       // 32 KB: this block's 1024-pt db slice
  __shared__ float m1s[128];

  const int tid  = threadIdx.x;
  const int lane = tid & 63;
  const int w    = tid >> 6;
  const int row  = lane & 31;
  const int hf   = lane >> 5;
  const short ONE = (short)0x3F80;    // bf16(1.0)

  // ---- A-frag: this lane's query point (R16-verbatim) ----
  const int qi = ic * 128 + w * 32 + row;
  const float qx = q_base[qi * 3 + 0];
  const float qy = q_base[qi * 3 + 1];
  const float qz = q_base[qi * 3 + 2];
  const float sx = -2.0f * qx, sy = -2.0f * qy, sz = -2.0f * qz;
  const unsigned short shx = f2bf(sx), shy = f2bf(sy), shz = f2bf(sz);
  const unsigned short slx = f2bf(sx - bf2f(shx));
  const unsigned short sly = f2bf(sy - bf2f(shy));
  const unsigned short slz = f2bf(sz - bf2f(shz));
  const float q2 = fmaf(qx, qx, fmaf(qy, qy, qz * qz));
  const unsigned short q2h = f2bf(q2);
  const unsigned short q2l = f2bf(q2 - bf2f(q2h));
  const s16x8 a0 = {(short)shx, (short)shy, (short)shz,
                    (short)shx, (short)shy, (short)shz,
                    (short)slx, (short)sly};
  const s16x8 a1 = {(short)slz, ONE, ONE, (short)q2h, (short)q2l, 0, 0, 0};
  const s16x8 afr = hf ? a1 : a0;

  // ---- stage this js slice: plain copy of prepacked frags (R16-verbatim) ----
#pragma unroll
  for (int k = 0; k < 8; ++k)
    yfrag[tid + k * 256] = dB[js * 2048 + tid + k * 256];
  __syncthreads();

  // ---- MFMA inner loop: R16 body + UB-free 2-deep prefetch ----
  float m1[16];
#pragma unroll
  for (int r = 0; r < 16; ++r) m1[r] = 3.4e38f;
  const f32x16 zc = {};
  const s16x8* base = &yfrag[0] + lane;     // ds addr = lane*16 + jt*1024 (imm)

  s16x8 c0 = base[0];
  s16x8 c1 = base[64];
#pragma unroll
  for (int jt = 0; jt < 32; jt += 2) {
    const int nj = (jt + 2) & 31;           // wraps to 0 on last iter (defined)
    const s16x8 n0 = base[nj * 64];
    const s16x8 n1 = base[(nj + 1) * 64];
    const f32x16 d0 = __builtin_amdgcn_mfma_f32_32x32x16_bf16(afr, c0, zc, 0, 0, 0);
    const f32x16 d1 = __builtin_amdgcn_mfma_f32_32x32x16_bf16(afr, c1, zc, 0, 0, 0);
#pragma unroll
    for (int r = 0; r < 16; ++r) m1[r] = fmin3f(d0[r], d1[r], m1[r]);
    c0 = n0; c1 = n1;
  }

  // ---- min across the 32 cols (R16-verbatim) ----
#pragma unroll
  for (int s = 1; s <= 16; s <<= 1) {
#pragma unroll
    for (int r = 0; r < 16; ++r) m1[r] = fminf(m1[r], __shfl_xor(m1[r], s));
  }

  // ---- park row mins in m1s (R16-verbatim) ----
  if ((lane & 31) == 0) {
#pragma unroll
    for (int r = 0; r < 16; ++r) {
      const int rw = (r & 3) + 8 * (r >> 2) + 4 * hf;
      m1s[w * 32 + rw] = m1[r];
    }
  }
  __syncthreads();

  // ---- cross-block combine via atomicMin on uint-cast floats (R16-verbatim) ----
  if (tid < 128) {
    const float v = fmaxf(m1s[tid], 0.0f);
    atomicMin(&wsmin[(size_t)dir * 65536 + (size_t)b * NP + ic * 128 + tid],
              __float_as_uint(v));
  }
}

__global__ __launch_bounds__(256) void chamfer_final(
    const unsigned* __restrict__ wsmin, float* __restrict__ out) {
  const int i = blockIdx.x * 256 + threadIdx.x;   // grid 512 -> 131072
  float s = sqrtf(__uint_as_float(wsmin[i]) + 1e-6f);
#pragma unroll
  for (int off = 32; off > 0; off >>= 1) s += __shfl_down(s, off);
  __shared__ float wsum[4];
  if ((threadIdx.x & 63) == 0) wsum[threadIdx.x >> 6] = s;
  __syncthreads();
  if (threadIdx.x == 0)
    atomicAdd(out, (wsum[0] + wsum[1] + wsum[2] + wsum[3]) * (1.0f / 65536.0f));
}

extern "C" void kernel_launch(void* const* d_in, const int* in_sizes, int n_in,
                              void* d_out, int out_size, void* d_ws, size_t ws_size,
                              hipStream_t stream) {
  const float* x = (const float*)d_in[0];
  const float* y = (const float*)d_in[1];
  float* out = (float*)d_out;
  unsigned* wsmin = (unsigned*)d_ws;              // 512 KB
  s16x8* wsfrag = (s16x8*)d_ws + U0;              // 4 MB of B-frags after it

  chamfer_pack<<<512, 256, 0, stream>>>(x, y, wsmin, wsfrag, out);
  chamfer_dir<<<NBLOCKS, BLK, 0, stream>>>(x, y, wsfrag, wsmin);
  chamfer_final<<<512, 256, 0, stream>>>(wsmin, out);
}

// Round 12
// 96.688 us; speedup vs baseline: 1.0311x; 1.0292x over previous
//
#include <hip/hip_runtime.h>

// ChamferLoss: x,y (16,4096,3) f32 -> scalar.
// R20: R19 passed -> __launch_bounds__(N,4) CONFIRMED as the miscompile
// trigger (5/5 fails with it, 4/4 passes without). This exonerates R14's
// js full-scan loop and R17's dual-A structure (both failed only under
// (,4)). R19 perf: dir 47.6us, VGPR still 52, MfmaUtil 13% -> ~85%
// stall-bound short-block churn + single dependent MFMA->min3 chain.
// R20 recombines the exonerated pieces, NO min-waves arg anywhere:
//  - dual-A: 2 query tiles/wave -> 2 independent MFMA->min3 chains (ILP),
//    2x arithmetic per staged byte;
//  - 2-slice js-loop: each block scans 2 of 4 slices -> launches, A-packs,
//    reduces, atomics halved (524K -> 262K).
// Grid 1024 = dir(2) x b(16) x jh(2) x ic(16); 4 blocks/CU, 4 waves/SIMD.
// Target: dir 15-25us, dur_us 72-84 (incl. fixed ~44us ws-fill tax).

#define NP 4096
#define NB 16
#define BLK 256
#define NBLOCKS 1024            // dir(2) x b(16) x jh(2) x ic(16)

typedef float f32x16 __attribute__((ext_vector_type(16)));
typedef short s16x8 __attribute__((ext_vector_type(8)));

// ws layout:
//   u32 [0, 131072): per-query running min (uint-cast f32):
//                    dir*65536 + b*4096 + q        (512 KB)
//   s16x8 units starting at U0 = 32768 (byte 512K):
//     XB @ +0      : [b][8192]  B-frags of x points (2 MB)
//     YB @ +131072 : [b][8192]  B-frags of y points (2 MB)
#define U0 32768

__device__ __forceinline__ float fmin3f(float a, float b, float c) {
  float d;
  asm("v_min3_f32 %0, %1, %2, %3" : "=v"(d) : "v"(a), "v"(b), "v"(c));
  return d;
}

__device__ __forceinline__ unsigned short f2bf(float v) {
  unsigned u = __float_as_uint(v);
  u += 0x7FFFu + ((u >> 16) & 1u);        // RNE to bf16
  return (unsigned short)(u >> 16);
}
__device__ __forceinline__ float bf2f(unsigned short s) {
  return __uint_as_float(((unsigned)s) << 16);
}

// K-slot layout (A = queries as rows, B = db points as cols), R12/R15/R16/R19-verified:
//  k0-2 : sh(x,y,z)*dh(x,y,z)   (s = -2*q, hi)    k9,10 : 1*d2h, 1*d2l
//  k3-5 : sh*dl                                   k11,12: q2h*1, q2l*1
//  k6-8 : sl*dh                                   k13-15: 0
// A-frag lane l: row=l%32, k=(l/32)*8+i ; B-frag: col=l%32, k=(l/32)*8+i.
// C/D: col=lane&31, row=(reg&3)+8*(reg>>2)+4*(lane>>5).

__global__ __launch_bounds__(256) void chamfer_pack(
    const float* __restrict__ x, const float* __restrict__ y,
    unsigned* __restrict__ wsmin, s16x8* __restrict__ wsfrag,
    float* __restrict__ out) {
  const int gid = blockIdx.x * 256 + threadIdx.x;   // grid 512 -> 131072
  if (gid == 0) out[0] = 0.0f;
  wsmin[gid] = 0x7F800000u;                         // +inf (min-region init)

  const int isY = gid >> 16;
  const int idx = gid & 65535;        // b*4096 + p
  const int p   = idx & 4095;
  const short ONE = (short)0x3F80;

  const float* src = (isY ? y : x) + (size_t)idx * 3;
  const float y0 = src[0], y1 = src[1], y2 = src[2];

  const unsigned short dh0 = f2bf(y0), dh1 = f2bf(y1), dh2 = f2bf(y2);
  const unsigned short dl0 = f2bf(y0 - bf2f(dh0));
  const unsigned short dl1 = f2bf(y1 - bf2f(dh1));
  const unsigned short dl2 = f2bf(y2 - bf2f(dh2));
  const float d2 = fmaf(y0, y0, fmaf(y1, y1, y2 * y2));
  const unsigned short d2h = f2bf(d2);
  const unsigned short d2l = f2bf(d2 - bf2f(d2h));
  const s16x8 h0 = {(short)dh0, (short)dh1, (short)dh2,
                    (short)dl0, (short)dl1, (short)dl2,
                    (short)dh0, (short)dh1};
  const s16x8 h1 = {(short)dh2, (short)d2h, (short)d2l, ONE, ONE, 0, 0, 0};

  // unit within [b] region: matches dir kernel's LDS layout (+32 for h1)
  const int u = (p >> 10) * 2048 + ((p >> 5) & 31) * 64 + (p & 31);
  s16x8* B = wsfrag + (isY ? 131072 : 0) + (size_t)(idx - p) * 2;  // b*8192
  B[u]      = h0;
  B[u + 32] = h1;
}

__global__ __launch_bounds__(BLK) void chamfer_dir(
    const float* __restrict__ x, const float* __restrict__ y,
    const s16x8* __restrict__ wsfrag, unsigned* __restrict__ wsmin) {
  const int bid = blockIdx.x;
  const int dir = bid >> 9;
  const int b   = (bid >> 5) & 15;
  const int jh  = (bid >> 4) & 1;
  const int ic  = bid & 15;

  // dir 0: queries = x rows, db = y cols (reference min1)
  // dir 1: queries = y rows, db = x cols (reference min2)
  const float* q_base = (dir == 0 ? x : y) + (size_t)b * NP * 3;
  const s16x8* dB = wsfrag + (dir == 0 ? 131072 : 0) + (size_t)b * 8192;

  __shared__ s16x8 yfrag[2048];       // 32 KB: one 1024-pt db slice
  __shared__ float m1s[256];

  const int tid  = threadIdx.x;
  const int lane = tid & 63;
  const int w    = tid >> 6;
  const int row  = lane & 31;
  const int hf   = lane >> 5;
  const short ONE = (short)0x3F80;    // bf16(1.0)

  // ---- A-frags: TWO query row-tiles per wave (R17 structure, exonerated) ----
  s16x8 afr0, afr1;
  {
    const int qi = ic * 256 + w * 64 + row;       // tile 2w
    const float qx = q_base[qi * 3 + 0];
    const float qy = q_base[qi * 3 + 1];
    const float qz = q_base[qi * 3 + 2];
    const float sx = -2.0f * qx, sy = -2.0f * qy, sz = -2.0f * qz;
    const unsigned short shx = f2bf(sx), shy = f2bf(sy), shz = f2bf(sz);
    const unsigned short slx = f2bf(sx - bf2f(shx));
    const unsigned short sly = f2bf(sy - bf2f(shy));
    const unsigned short slz = f2bf(sz - bf2f(shz));
    const float q2 = fmaf(qx, qx, fmaf(qy, qy, qz * qz));
    const unsigned short q2h = f2bf(q2);
    const unsigned short q2l = f2bf(q2 - bf2f(q2h));
    const s16x8 a0 = {(short)shx, (short)shy, (short)shz,
                      (short)shx, (short)shy, (short)shz,
                      (short)slx, (short)sly};
    const s16x8 a1 = {(short)slz, ONE, ONE, (short)q2h, (short)q2l, 0, 0, 0};
    afr0 = hf ? a1 : a0;
  }
  {
    const int qi = ic * 256 + w * 64 + 32 + row;  // tile 2w+1
    const float qx = q_base[qi * 3 + 0];
    const float qy = q_base[qi * 3 + 1];
    const float qz = q_base[qi * 3 + 2];
    const float sx = -2.0f * qx, sy = -2.0f * qy, sz = -2.0f * qz;
    const unsigned short shx = f2bf(sx), shy = f2bf(sy), shz = f2bf(sz);
    const unsigned short slx = f2bf(sx - bf2f(shx));
    const unsigned short sly = f2bf(sy - bf2f(shy));
    const unsigned short slz = f2bf(sz - bf2f(shz));
    const float q2 = fmaf(qx, qx, fmaf(qy, qy, qz * qz));
    const unsigned short q2h = f2bf(q2);
    const unsigned short q2l = f2bf(q2 - bf2f(q2h));
    const s16x8 a0 = {(short)shx, (short)shy, (short)shz,
                      (short)shx, (short)shy, (short)shz,
                      (short)slx, (short)sly};
    const s16x8 a1 = {(short)slz, ONE, ONE, (short)q2h, (short)q2l, 0, 0, 0};
    afr1 = hf ? a1 : a0;
  }

  float m0[16], m1[16];
#pragma unroll
  for (int r = 0; r < 16; ++r) { m0[r] = 3.4e38f; m1[r] = 3.4e38f; }
  const f32x16 zc = {};
  const s16x8* base = &yfrag[0] + lane;     // ds addr = lane*16 + jt*1024 (imm)

  // ---- 2-slice scan (R14 js-loop topology, exonerated) ----
  for (int s = 0; s < 2; ++s) {
    const int js = jh * 2 + s;
    __syncthreads();                  // previous slice fully consumed
#pragma unroll
    for (int k = 0; k < 8; ++k)
      yfrag[tid + k * 256] = dB[js * 2048 + tid + k * 256];
    __syncthreads();

    // dual-chain MFMA loop + UB-free wrap prefetch (R19-verified prefetch)
    s16x8 c0 = base[0];
    s16x8 c1 = base[64];
#pragma unroll
    for (int jt = 0; jt < 32; jt += 2) {
      const int nj = (jt + 2) & 31;         // wraps to 0 on last iter (defined)
      const s16x8 n0 = base[nj * 64];
      const s16x8 n1 = base[(nj + 1) * 64];
      const f32x16 d00 = __builtin_amdgcn_mfma_f32_32x32x16_bf16(afr0, c0, zc, 0, 0, 0);
      const f32x16 d01 = __builtin_amdgcn_mfma_f32_32x32x16_bf16(afr0, c1, zc, 0, 0, 0);
      const f32x16 d10 = __builtin_amdgcn_mfma_f32_32x32x16_bf16(afr1, c0, zc, 0, 0, 0);
      const f32x16 d11 = __builtin_amdgcn_mfma_f32_32x32x16_bf16(afr1, c1, zc, 0, 0, 0);
#pragma unroll
      for (int r = 0; r < 16; ++r) m0[r] = fmin3f(d00[r], d01[r], m0[r]);
#pragma unroll
      for (int r = 0; r < 16; ++r) m1[r] = fmin3f(d10[r], d11[r], m1[r]);
      c0 = n0; c1 = n1;
    }
  }

  // ---- min across the 32 cols (both tiles) ----
#pragma unroll
  for (int s = 1; s <= 16; s <<= 1) {
#pragma unroll
    for (int r = 0; r < 16; ++r) {
      m0[r] = fminf(m0[r], __shfl_xor(m0[r], s));
      m1[r] = fminf(m1[r], __shfl_xor(m1[r], s));
    }
  }

  // ---- park row mins (verified rw mapping; tiles 2w, 2w+1) ----
  if ((lane & 31) == 0) {
#pragma unroll
    for (int r = 0; r < 16; ++r) {
      const int rw = (r & 3) + 8 * (r >> 2) + 4 * hf;
      m1s[w * 64 + rw]      = m0[r];
      m1s[w * 64 + 32 + rw] = m1[r];
    }
  }
  __syncthreads();

  // ---- cross-block combine via atomicMin on uint-cast floats ----
  {
    const float v = fmaxf(m1s[tid], 0.0f);
    atomicMin(&wsmin[(size_t)dir * 65536 + (size_t)b * NP + ic * 256 + tid],
              __float_as_uint(v));
  }
}

__global__ __launch_bounds__(256) void chamfer_final(
    const unsigned* __restrict__ wsmin, float* __restrict__ out) {
  const int i = blockIdx.x * 256 + threadIdx.x;   // grid 512 -> 131072
  float s = sqrtf(__uint_as_float(wsmin[i]) + 1e-6f);
#pragma unroll
  for (int off = 32; off > 0; off >>= 1) s += __shfl_down(s, off);
  __shared__ float wsum[4];
  if ((threadIdx.x & 63) == 0) wsum[threadIdx.x >> 6] = s;
  __syncthreads();
  if (threadIdx.x == 0)
    atomicAdd(out, (wsum[0] + wsum[1] + wsum[2] + wsum[3]) * (1.0f / 65536.0f));
}

extern "C" void kernel_launch(void* const* d_in, const int* in_sizes, int n_in,
                              void* d_out, int out_size, void* d_ws, size_t ws_size,
                              hipStream_t stream) {
  const float* x = (const float*)d_in[0];
  const float* y = (const float*)d_in[1];
  float* out = (float*)d_out;
  unsigned* wsmin = (unsigned*)d_ws;              // 512 KB
  s16x8* wsfrag = (s16x8*)d_ws + U0;              // 4 MB of B-frags after it

  chamfer_pack<<<512, 256, 0, stream>>>(x, y, wsmin, wsfrag, out);
  chamfer_dir<<<NBLOCKS, BLK, 0, stream>>>(x, y, wsfrag, wsmin);
  chamfer_final<<<512, 256, 0, stream>>>(wsmin, out);
}